// Round 3
// baseline (745.442 us; speedup 1.0000x reference)
//
#include <hip/hip_runtime.h>
#include <hip/hip_bf16.h>

#define NN 100000
#define NE 1600000
#define NT 6250      // NN/16 node-tiles for MFMA

#define NBUCK  511       // buckets of BRANGE destination nodes
#define BRANGE 196       // fits 8-bit local id
#define CAPB   3584      // bucket capacity: mean 3136, sigma 56 -> 8-sigma margin
#define CHUNK  2048      // edges per bin block
#define NCH    782       // ceil(NE/CHUNK)

typedef __attribute__((ext_vector_type(8))) short bf16x8;
typedef __attribute__((ext_vector_type(4))) float f32x4;

__device__ inline float2 bf16x2_unpack(unsigned v) {
    float2 r;
    r.x = __uint_as_float(v << 16);
    r.y = __uint_as_float(v & 0xffff0000u);
    return r;
}
__device__ inline unsigned bf16x2_pack(float a, float b) {
    __hip_bfloat162 h2(__float2bfloat16(a), __float2bfloat16(b));
    unsigned u;
    __builtin_memcpy(&u, &h2, 4);
    return u;
}

// ---- phase 1: lean bucket binning. No scan, no LDS staging sort: per-block
//      bucket hist -> one global reserve atomic per (block,bucket) -> direct
//      clustered writes (runs of ~4 edges; line amplification ~4x = harmless).
//      Also builds the global degree histogram (fire-and-forget atomics). ----
__global__ __launch_bounds__(256) void bin2_kernel(const int* __restrict__ rows,
                                                   const int* __restrict__ cols,
                                                   int* __restrict__ cur,      // stride 16 dwords: 1 counter per 64B line
                                                   int* __restrict__ deg,
                                                   unsigned* __restrict__ eb) {
    __shared__ int hist[512];
    __shared__ int lcur[512];
    int t = threadIdx.x;
    int base = blockIdx.x * CHUNK;
    int cnt = min(CHUNK, NE - base);

    hist[t] = 0; hist[t + 256] = 0;
    __syncthreads();
    #pragma unroll
    for (int k = 0; k < CHUNK / 256; k++) {
        int i = k * 256 + t;
        if (i < cnt) {
            int c = cols[base + i];
            atomicAdd(&deg[c], 1);                       // global, no return: non-blocking
            atomicAdd(&hist[(unsigned)c / BRANGE], 1);
        }
    }
    __syncthreads();
    // bulk-reserve a run per nonzero bucket; lcur = absolute cursor in bucket
    #pragma unroll
    for (int u = t; u < 512; u += 256) {
        int h = hist[u];
        lcur[u] = h ? atomicAdd(&cur[u * 16], h) : 0;
    }
    __syncthreads();
    #pragma unroll
    for (int k = 0; k < CHUNK / 256; k++) {
        int i = k * 256 + t;
        if (i < cnt) {
            int c = cols[base + i];
            int r = rows[base + i];
            int bkt = (unsigned)c / BRANGE;
            int p = atomicAdd(&lcur[bkt], 1);
            if (p < CAPB)
                eb[(size_t)bkt * CAPB + p] = ((unsigned)(c - bkt * BRANGE) << 24) | (unsigned)r;
        }
    }
}

// ---- xs = bf16(x * rsqrt(deg+1)) : standalone, high-TLP dense stream ----
__global__ __launch_bounds__(256) void xscale_kernel(const float* __restrict__ x,
                                                     const int* __restrict__ deg,
                                                     unsigned* __restrict__ xs) {
    int i = blockIdx.x * 256 + threadIdx.x;           // NN*32 threads exactly
    int n = i >> 5;
    int d = (i & 31) * 2;
    float2 v = *(const float2*)(x + (size_t)n * 64 + d);
    float dv = rsqrtf((float)(deg[n] + 1));
    xs[i] = bf16x2_pack(v.x * dv, v.y * dv);
}

// ---- fused nodesort+gather: one block per bucket. Stream the bucket's edge
//      records (coalesced), random-gather xs rows with 16-deep MLP per lane,
//      ds_add_f32 into acc[196][64] (dim split low/high -> 2-way banks = free),
//      then finalize self-loop + D^-1/2 and emit bf16 rows. ----
__global__ __launch_bounds__(512) void gacc_kernel(const int* __restrict__ cur,
                                                   const unsigned* __restrict__ eb,
                                                   const int* __restrict__ deg,
                                                   const unsigned* __restrict__ xs,
                                                   unsigned* __restrict__ hbu) {
    __shared__ float acc[BRANGE * 64];
    int b = blockIdx.x;
    int t = threadIdx.x;
    int lane = t & 63;
    int wave = t >> 6;
    int sub = lane >> 5;            // which of 2 edges this half-wave handles
    int dp = lane & 31;             // dword (dim pair) within row

    int cnt = min(cur[b * 16], CAPB);
    const unsigned* seg = eb + (size_t)b * CAPB;

    #pragma unroll
    for (int i = t; i < BRANGE * 16; i += 512)
        ((float4*)acc)[i] = make_float4(0.f, 0.f, 0.f, 0.f);
    __syncthreads();

    for (int wbase = wave * 64; wbase < cnt; wbase += 512) {
        int nrec = min(64, cnt - wbase);
        unsigned rec = (lane < nrec) ? seg[wbase + lane] : 0u;
        unsigned rec0 = __shfl(rec, 0);                 // always valid (wbase < cnt)
        #pragma unroll
        for (int c = 0; c < 64; c += 32) {
            unsigned rr[16];
            unsigned vb[16];
            #pragma unroll
            for (int j = 0; j < 16; j++) {
                int k = c + 2 * j + sub;
                unsigned s = __shfl(rec, k);
                rr[j] = s;
                unsigned sa = (k < nrec) ? s : rec0;    // clamp OOB to a live line
                vb[j] = xs[(size_t)(sa & 0xFFFFFFu) * 32 + dp];
            }
            #pragma unroll
            for (int j = 0; j < 16; j++) {
                int k = c + 2 * j + sub;
                if (k < nrec) {
                    float2 f = bf16x2_unpack(vb[j]);
                    int local = rr[j] >> 24;
                    atomicAdd(&acc[local * 64 + dp], f.x);        // dims 2dp   -> banks 0..31
                    atomicAdd(&acc[local * 64 + 32 + dp], f.y);   // dims 2dp+1 -> banks 0..31
                }
            }
        }
    }
    __syncthreads();

    int nloc = min(BRANGE, NN - b * BRANGE);
    for (int i = t; i < nloc * 32; i += 512) {
        int nl = i >> 5;
        int d = i & 31;
        int n = b * BRANGE + nl;
        float2 f = bf16x2_unpack(xs[(size_t)n * 32 + d]);
        float dn = rsqrtf((float)(deg[n] + 1));
        float a0 = (acc[nl * 64 + d] + f.x) * dn;
        float a1 = (acc[nl * 64 + 32 + d] + f.y) * dn;
        hbu[(size_t)n * 32 + d] = bf16x2_pack(a0, a1);
    }
}

// ---- pack Wcat[64 x 192] (3 experts side by side) into B-fragment order, bf16 ----
__global__ void wpack_kernel(const float* __restrict__ W, __hip_bfloat16* __restrict__ Bp) {
    int idx = blockIdx.x * 256 + threadIdx.x;         // 12288 total
    if (idx >= 12288) return;
    int j    = idx & 7;
    int lane = (idx >> 3) & 63;
    int rest = idx >> 9;                              // half*12 + t
    int t    = rest % 12;
    int kh   = rest / 12;
    int k    = kh * 32 + (lane >> 4) * 8 + j;
    int col  = t * 16 + (lane & 15);
    int i    = col >> 6;
    int d    = col & 63;
    Bp[idx] = __float2bfloat16(W[(i * 64 + k) * 64 + d]);
}

// ---- dense: [16-node tile] x [192 outs], K=64 bf16 MFMA; fused bias+relu+gate mix ----
__global__ __launch_bounds__(256) void mfma_kernel(const __hip_bfloat16* __restrict__ hb,
                                                   const short* __restrict__ Bp,
                                                   const float* __restrict__ b,
                                                   const float* __restrict__ gf,
                                                   const float* __restrict__ Wg,
                                                   float* __restrict__ out) {
    int wave = threadIdx.x >> 6;
    int lane = threadIdx.x & 63;
    int tile = blockIdx.x * 4 + wave;
    if (tile >= NT) return;
    int n0 = tile * 16;
    int m = lane & 15, quad = lane >> 4;

    const short* hrow = (const short*)hb + ((size_t)(n0 + m)) * 64 + quad * 8;
    bf16x8 a0 = *(const bf16x8*)(hrow);
    bf16x8 a1 = *(const bf16x8*)(hrow + 32);

    f32x4 acc[12];
    #pragma unroll
    for (int t = 0; t < 12; t++) acc[t] = (f32x4)(0.0f);

    #pragma unroll
    for (int kh = 0; kh < 2; kh++) {
        bf16x8 a = kh ? a1 : a0;
        #pragma unroll
        for (int t = 0; t < 12; t++) {
            bf16x8 bf = *(const bf16x8*)(Bp + ((size_t)((kh * 12 + t) * 64 + lane)) * 8);
            acc[t] = __builtin_amdgcn_mfma_f32_16x16x32_bf16(a, bf, acc[t], 0, 0, 0);
        }
    }

    float wg[12];
    #pragma unroll
    for (int k = 0; k < 12; k++) wg[k] = Wg[k];       // [GATE_C=4][EXPERTS=3] row-major

    #pragma unroll
    for (int reg = 0; reg < 4; reg++) {
        int n = n0 + quad * 4 + reg;
        float4 g = ((const float4*)gf)[n];
        float l0 = (g.x*wg[0] + g.y*wg[3] + g.z*wg[6] + g.w*wg[9])  * (1.0f/101.0f);
        float l1 = (g.x*wg[1] + g.y*wg[4] + g.z*wg[7] + g.w*wg[10]) * (1.0f/101.0f);
        float l2 = (g.x*wg[2] + g.y*wg[5] + g.z*wg[8] + g.w*wg[11]) * (1.0f/101.0f);
        float mx = fmaxf(l0, fmaxf(l1, l2));
        float e0 = __expf(l0 - mx), e1 = __expf(l1 - mx), e2 = __expf(l2 - mx);
        float inv = 1.0f / (e0 + e1 + e2);
        float g0 = e0 * inv, g1 = e1 * inv, g2 = e2 * inv;
        #pragma unroll
        for (int dpos = 0; dpos < 4; dpos++) {
            int d = dpos * 16 + m;
            float v0 = acc[0*4 + dpos][reg] + b[0*64 + d];
            float v1 = acc[1*4 + dpos][reg] + b[1*64 + d];
            float v2 = acc[2*4 + dpos][reg] + b[2*64 + d];
            float o = g0 * fmaxf(v0, 0.f) + g1 * fmaxf(v1, 0.f) + g2 * fmaxf(v2, 0.f);
            out[(size_t)n * 64 + d] = o;
        }
    }
}

extern "C" void kernel_launch(void* const* d_in, const int* in_sizes, int n_in,
                              void* d_out, int out_size, void* d_ws, size_t ws_size,
                              hipStream_t stream) {
    const float* x  = (const float*)d_in[0];
    const int*   ei = (const int*)d_in[1];
    const float* gf = (const float*)d_in[2];
    const float* W  = (const float*)d_in[3];
    const float* b  = (const float*)d_in[4];
    const float* Wg = (const float*)d_in[5];
    float* out = (float*)d_out;
    const int* rows = ei;        // edge_index[0] (sources)
    const int* cols = ei + NE;   // edge_index[1] (targets)

    char* ws = (char*)d_ws;
    size_t off = 0;
    auto alloc = [&](size_t bytes) {
        char* p = ws + off;
        off = (off + bytes + 255) & ~(size_t)255;
        return p;
    };
    int*            cur = (int*)alloc(512 * 16 * 4);          // 1 counter / 64B line
    int*            deg = (int*)alloc((size_t)NN * 4);        // adjacent to cur: one memset
    unsigned*       eb  = (unsigned*)alloc((size_t)NBUCK * CAPB * 4);
    unsigned*       xs  = (unsigned*)alloc((size_t)NN * 32 * 4);
    unsigned*       hbu = (unsigned*)alloc((size_t)NN * 32 * 4);
    __hip_bfloat16* Bp  = (__hip_bfloat16*)alloc(12288 * 2);

    hipMemsetAsync(cur, 0, 512 * 16 * 4 + (size_t)NN * 4, stream);

    bin2_kernel<<<NCH, 256, 0, stream>>>(rows, cols, cur, deg, eb);
    xscale_kernel<<<NN * 32 / 256, 256, 0, stream>>>(x, deg, xs);
    wpack_kernel<<<48, 256, 0, stream>>>(W, Bp);
    gacc_kernel<<<NBUCK, 512, 0, stream>>>(cur, eb, deg, xs, hbu);
    mfma_kernel<<<(NT + 3) / 4, 256, 0, stream>>>((const __hip_bfloat16*)hbu,
                                                  (const short*)Bp, b, gf, Wg, out);
}

// Round 4
// 244.061 us; speedup vs baseline: 3.0543x; 3.0543x over previous
//
#include <hip/hip_runtime.h>
#include <hip/hip_bf16.h>

#define NN 100000
#define NE 1600000
#define NT 6250      // NN/16 node-tiles for MFMA

#define NBUCK  511       // buckets of BRANGE destination nodes
#define BRANGE 196       // fits 8-bit local id
#define CAPB   3584      // bucket capacity: mean 3136, sigma 56 -> 8-sigma margin
#define CHUNK  2048      // edges per bin block
#define NCH    782       // ceil(NE/CHUNK)

typedef __attribute__((ext_vector_type(8))) short bf16x8;
typedef __attribute__((ext_vector_type(4))) float f32x4;

__device__ inline float2 bf16x2_unpack(unsigned v) {
    float2 r;
    r.x = __uint_as_float(v << 16);
    r.y = __uint_as_float(v & 0xffff0000u);
    return r;
}
__device__ inline unsigned bf16x2_pack(float a, float b) {
    __hip_bfloat162 h2(__float2bfloat16(a), __float2bfloat16(b));
    unsigned u;
    __builtin_memcpy(&u, &h2, 4);
    return u;
}

// ---- phase 1: lean bucket binning. No scan, no LDS staging sort: per-block
//      bucket hist -> one global reserve atomic per (block,bucket) -> direct
//      clustered writes (runs of ~4 edges; line amplification ~4x = harmless).
//      Also builds the global degree histogram (fire-and-forget atomics). ----
__global__ __launch_bounds__(256) void bin2_kernel(const int* __restrict__ rows,
                                                   const int* __restrict__ cols,
                                                   int* __restrict__ cur,      // stride 16 dwords: 1 counter per 64B line
                                                   int* __restrict__ deg,
                                                   unsigned* __restrict__ eb) {
    __shared__ int hist[512];
    __shared__ int lcur[512];
    int t = threadIdx.x;
    int base = blockIdx.x * CHUNK;
    int cnt = min(CHUNK, NE - base);

    hist[t] = 0; hist[t + 256] = 0;
    __syncthreads();
    #pragma unroll
    for (int k = 0; k < CHUNK / 256; k++) {
        int i = k * 256 + t;
        if (i < cnt) {
            int c = cols[base + i];
            atomicAdd(&deg[c], 1);                       // global, no return: non-blocking
            atomicAdd(&hist[(unsigned)c / BRANGE], 1);
        }
    }
    __syncthreads();
    // bulk-reserve a run per nonzero bucket; lcur = absolute cursor in bucket
    #pragma unroll
    for (int u = t; u < 512; u += 256) {
        int h = hist[u];
        lcur[u] = h ? atomicAdd(&cur[u * 16], h) : 0;
    }
    __syncthreads();
    #pragma unroll
    for (int k = 0; k < CHUNK / 256; k++) {
        int i = k * 256 + t;
        if (i < cnt) {
            int c = cols[base + i];
            int r = rows[base + i];
            int bkt = (unsigned)c / BRANGE;
            int p = atomicAdd(&lcur[bkt], 1);
            if (p < CAPB)
                eb[(size_t)bkt * CAPB + p] = ((unsigned)(c - bkt * BRANGE) << 24) | (unsigned)r;
        }
    }
}

// ---- xs = bf16(x * rsqrt(deg+1)) : standalone, high-TLP dense stream ----
__global__ __launch_bounds__(256) void xscale_kernel(const float* __restrict__ x,
                                                     const int* __restrict__ deg,
                                                     unsigned* __restrict__ xs) {
    int i = blockIdx.x * 256 + threadIdx.x;           // NN*32 threads exactly
    int n = i >> 5;
    int d = (i & 31) * 2;
    float2 v = *(const float2*)(x + (size_t)n * 64 + d);
    float dv = rsqrtf((float)(deg[n] + 1));
    xs[i] = bf16x2_pack(v.x * dv, v.y * dv);
}

// ---- fused sort+gather: one block per bucket. Stage records in LDS, build
//      per-node runs via hist+scan+rank (INT LDS atomics only), then 16-lane
//      group register gather (8 lines in flight/group) reading indices from
//      LDS. No srcs2 global round-trip, no float LDS atomics. ----
__global__ __launch_bounds__(512) void sortgather_kernel(const int* __restrict__ cur,
                                                         const unsigned* __restrict__ eb,
                                                         const unsigned* __restrict__ xs,
                                                         unsigned* __restrict__ hbu) {
    __shared__ unsigned recs[CAPB];
    __shared__ unsigned srcl[CAPB];
    __shared__ int hist[256];
    __shared__ int sx[256];
    __shared__ int nstart[BRANGE];
    __shared__ int lcur[BRANGE];
    __shared__ int ndeg[BRANGE];
    int b = blockIdx.x, t = threadIdx.x;
    if (t < 256) hist[t] = 0;
    __syncthreads();
    int cnt = min(cur[b * 16], CAPB);
    const unsigned* seg = eb + (size_t)b * CAPB;
    for (int i = t; i < cnt; i += 512) {
        unsigned r = seg[i];
        recs[i] = r;
        atomicAdd(&hist[r >> 24], 1);
    }
    __syncthreads();
    if (t < 256) sx[t] = hist[t];
    __syncthreads();
    #pragma unroll
    for (int off = 1; off < 256; off <<= 1) {
        int v = (t < 256 && t >= off) ? sx[t - off] : 0;
        __syncthreads();
        if (t < 256) sx[t] += v;
        __syncthreads();
    }
    if (t < BRANGE) {
        int ex = (t > 0) ? sx[t - 1] : 0;
        nstart[t] = ex;
        lcur[t] = ex;
        ndeg[t] = hist[t];
    }
    __syncthreads();
    for (int i = t; i < cnt; i += 512) {
        unsigned r = recs[i];
        int p = atomicAdd(&lcur[r >> 24], 1);
        srcl[p] = r & 0xFFFFFFu;
    }
    __syncthreads();

    // gather phase: 32 groups of 16 lanes; group handles one node at a time
    int lane = t & 63;
    int wave = t >> 6;
    int g  = lane >> 4;
    int gl = lane & 15;
    int gb = g << 4;
    int group = wave * 4 + g;                          // 0..31
    const uint2* xsv = (const uint2*)xs;               // 8B per lane per row

    for (int nl = group; nl < BRANGE; nl += 32) {
        int dg = ndeg[nl];
        int st = nstart[nl];
        float4 acc = make_float4(0.f, 0.f, 0.f, 0.f);
        for (int base = 0; base < dg; base += 16) {
            int idx = 0;
            if (base + gl < dg) idx = (int)srcl[st + base + gl];
            int s0 = __shfl(idx, gb);                  // always valid (base < dg)
            #pragma unroll
            for (int c = 0; c < 16; c += 8) {
                uint2 v[8];
                #pragma unroll
                for (int j = 0; j < 8; j++) {
                    int s = __shfl(idx, gb + c + j);
                    s = (base + c + j < dg) ? s : s0;  // clamp OOB to a live line
                    v[j] = xsv[(size_t)s * 16 + gl];
                }
                #pragma unroll
                for (int j = 0; j < 8; j++) {
                    if (base + c + j < dg) {
                        float2 f0 = bf16x2_unpack(v[j].x);
                        float2 f1 = bf16x2_unpack(v[j].y);
                        acc.x += f0.x; acc.y += f0.y;
                        acc.z += f1.x; acc.w += f1.y;
                    }
                }
            }
        }
        int n = b * BRANGE + nl;
        if (n < NN) {
            uint2 svu = xsv[(size_t)n * 16 + gl];
            float2 sv0 = bf16x2_unpack(svu.x);
            float2 sv1 = bf16x2_unpack(svu.y);
            float dn = rsqrtf((float)(dg + 1));
            uint2 o;
            o.x = bf16x2_pack((acc.x + sv0.x) * dn, (acc.y + sv0.y) * dn);
            o.y = bf16x2_pack((acc.z + sv1.x) * dn, (acc.w + sv1.y) * dn);
            ((uint2*)hbu)[(size_t)n * 16 + gl] = o;
        }
    }
}

// ---- pack Wcat[64 x 192] (3 experts side by side) into B-fragment order, bf16 ----
__global__ void wpack_kernel(const float* __restrict__ W, __hip_bfloat16* __restrict__ Bp) {
    int idx = blockIdx.x * 256 + threadIdx.x;         // 12288 total
    if (idx >= 12288) return;
    int j    = idx & 7;
    int lane = (idx >> 3) & 63;
    int rest = idx >> 9;                              // half*12 + t
    int t    = rest % 12;
    int kh   = rest / 12;
    int k    = kh * 32 + (lane >> 4) * 8 + j;
    int col  = t * 16 + (lane & 15);
    int i    = col >> 6;
    int d    = col & 63;
    Bp[idx] = __float2bfloat16(W[(i * 64 + k) * 64 + d]);
}

// ---- dense: [16-node tile] x [192 outs], K=64 bf16 MFMA; fused bias+relu+gate mix ----
__global__ __launch_bounds__(256) void mfma_kernel(const __hip_bfloat16* __restrict__ hb,
                                                   const short* __restrict__ Bp,
                                                   const float* __restrict__ b,
                                                   const float* __restrict__ gf,
                                                   const float* __restrict__ Wg,
                                                   float* __restrict__ out) {
    int wave = threadIdx.x >> 6;
    int lane = threadIdx.x & 63;
    int tile = blockIdx.x * 4 + wave;
    if (tile >= NT) return;
    int n0 = tile * 16;
    int m = lane & 15, quad = lane >> 4;

    const short* hrow = (const short*)hb + ((size_t)(n0 + m)) * 64 + quad * 8;
    bf16x8 a0 = *(const bf16x8*)(hrow);
    bf16x8 a1 = *(const bf16x8*)(hrow + 32);

    f32x4 acc[12];
    #pragma unroll
    for (int t = 0; t < 12; t++) acc[t] = (f32x4)(0.0f);

    #pragma unroll
    for (int kh = 0; kh < 2; kh++) {
        bf16x8 a = kh ? a1 : a0;
        #pragma unroll
        for (int t = 0; t < 12; t++) {
            bf16x8 bf = *(const bf16x8*)(Bp + ((size_t)((kh * 12 + t) * 64 + lane)) * 8);
            acc[t] = __builtin_amdgcn_mfma_f32_16x16x32_bf16(a, bf, acc[t], 0, 0, 0);
        }
    }

    float wg[12];
    #pragma unroll
    for (int k = 0; k < 12; k++) wg[k] = Wg[k];       // [GATE_C=4][EXPERTS=3] row-major

    #pragma unroll
    for (int reg = 0; reg < 4; reg++) {
        int n = n0 + quad * 4 + reg;
        float4 g = ((const float4*)gf)[n];
        float l0 = (g.x*wg[0] + g.y*wg[3] + g.z*wg[6] + g.w*wg[9])  * (1.0f/101.0f);
        float l1 = (g.x*wg[1] + g.y*wg[4] + g.z*wg[7] + g.w*wg[10]) * (1.0f/101.0f);
        float l2 = (g.x*wg[2] + g.y*wg[5] + g.z*wg[8] + g.w*wg[11]) * (1.0f/101.0f);
        float mx = fmaxf(l0, fmaxf(l1, l2));
        float e0 = __expf(l0 - mx), e1 = __expf(l1 - mx), e2 = __expf(l2 - mx);
        float inv = 1.0f / (e0 + e1 + e2);
        float g0 = e0 * inv, g1 = e1 * inv, g2 = e2 * inv;
        #pragma unroll
        for (int dpos = 0; dpos < 4; dpos++) {
            int d = dpos * 16 + m;
            float v0 = acc[0*4 + dpos][reg] + b[0*64 + d];
            float v1 = acc[1*4 + dpos][reg] + b[1*64 + d];
            float v2 = acc[2*4 + dpos][reg] + b[2*64 + d];
            float o = g0 * fmaxf(v0, 0.f) + g1 * fmaxf(v1, 0.f) + g2 * fmaxf(v2, 0.f);
            out[(size_t)n * 64 + d] = o;
        }
    }
}

extern "C" void kernel_launch(void* const* d_in, const int* in_sizes, int n_in,
                              void* d_out, int out_size, void* d_ws, size_t ws_size,
                              hipStream_t stream) {
    const float* x  = (const float*)d_in[0];
    const int*   ei = (const int*)d_in[1];
    const float* gf = (const float*)d_in[2];
    const float* W  = (const float*)d_in[3];
    const float* b  = (const float*)d_in[4];
    const float* Wg = (const float*)d_in[5];
    float* out = (float*)d_out;
    const int* rows = ei;        // edge_index[0] (sources)
    const int* cols = ei + NE;   // edge_index[1] (targets)

    char* ws = (char*)d_ws;
    size_t off = 0;
    auto alloc = [&](size_t bytes) {
        char* p = ws + off;
        off = (off + bytes + 255) & ~(size_t)255;
        return p;
    };
    int*            cur = (int*)alloc(512 * 16 * 4);          // 1 counter / 64B line
    int*            deg = (int*)alloc((size_t)NN * 4);        // adjacent to cur: one memset
    unsigned*       eb  = (unsigned*)alloc((size_t)NBUCK * CAPB * 4);
    unsigned*       xs  = (unsigned*)alloc((size_t)NN * 32 * 4);
    unsigned*       hbu = (unsigned*)alloc((size_t)NN * 32 * 4);
    __hip_bfloat16* Bp  = (__hip_bfloat16*)alloc(12288 * 2);

    hipMemsetAsync(cur, 0, 512 * 16 * 4 + (size_t)NN * 4, stream);

    bin2_kernel<<<NCH, 256, 0, stream>>>(rows, cols, cur, deg, eb);
    xscale_kernel<<<NN * 32 / 256, 256, 0, stream>>>(x, deg, xs);
    wpack_kernel<<<48, 256, 0, stream>>>(W, Bp);
    sortgather_kernel<<<NBUCK, 512, 0, stream>>>(cur, eb, xs, hbu);
    mfma_kernel<<<(NT + 3) / 4, 256, 0, stream>>>((const __hip_bfloat16*)hbu,
                                                  (const short*)Bp, b, gf, Wg, out);
}

// Round 5
// 178.547 us; speedup vs baseline: 4.1751x; 1.3669x over previous
//
#include <hip/hip_runtime.h>
#include <hip/hip_bf16.h>

#define NN 100000
#define NE 1600000
#define NT 6250      // NN/16 node-tiles for MFMA

#define NBUCK  511       // buckets of BRANGE destination nodes
#define BRANGE 196       // fits 8-bit local id
#define CAPB   3584      // bucket capacity: mean 3136, sigma 56 -> 8-sigma margin
#define CHUNK  2048      // edges per bin block
#define NCH    782       // ceil(NE/CHUNK)

typedef __attribute__((ext_vector_type(8))) short bf16x8;
typedef __attribute__((ext_vector_type(4))) float f32x4;

__device__ inline float2 bf16x2_unpack(unsigned v) {
    float2 r;
    r.x = __uint_as_float(v << 16);
    r.y = __uint_as_float(v & 0xffff0000u);
    return r;
}
__device__ inline unsigned bf16x2_pack(float a, float b) {
    __hip_bfloat162 h2(__float2bfloat16(a), __float2bfloat16(b));
    unsigned u;
    __builtin_memcpy(&u, &h2, 4);
    return u;
}

// ---- phase 1: block-local counting sort by bucket + bulk-reserved dense runs
//      (round-1 proven version; LDS staging buys line-coalesced eb writes) ----
__global__ __launch_bounds__(256) void bin_kernel(const int* __restrict__ rows,
                                                  const int* __restrict__ cols,
                                                  int* __restrict__ cur,   // padded: 1 counter / 64B line
                                                  unsigned* __restrict__ eb) {
    __shared__ int hist[512];
    __shared__ int excl[512];
    __shared__ int lcur[512];
    __shared__ int gbase[512];
    __shared__ int s2[256];
    __shared__ unsigned staged[CHUNK];
    __shared__ unsigned short bktarr[CHUNK];
    int t = threadIdx.x;
    int base = blockIdx.x * CHUNK;
    int cnt = min(CHUNK, NE - base);

    hist[t] = 0; hist[t + 256] = 0;
    __syncthreads();
    #pragma unroll
    for (int k = 0; k < CHUNK / 256; k++) {
        int i = k * 256 + t;
        if (i < cnt) {
            int c = cols[base + i];
            atomicAdd(&hist[(unsigned)c / BRANGE], 1);
        }
    }
    __syncthreads();
    // exclusive scan of 512 entries via pair trick (256-thread Hillis-Steele)
    int a0 = hist[2 * t], a1 = hist[2 * t + 1];
    s2[t] = a0 + a1;
    __syncthreads();
    #pragma unroll
    for (int off = 1; off < 256; off <<= 1) {
        int v = (t >= off) ? s2[t - off] : 0;
        __syncthreads();
        s2[t] += v;
        __syncthreads();
    }
    int pe = (t > 0) ? s2[t - 1] : 0;
    excl[2 * t] = pe;      excl[2 * t + 1] = pe + a0;
    lcur[2 * t] = pe;      lcur[2 * t + 1] = pe + a0;
    gbase[2 * t]     = a0 ? atomicAdd(cur + 2 * t * 16, a0) : 0;
    gbase[2 * t + 1] = a1 ? atomicAdd(cur + (2 * t + 1) * 16, a1) : 0;
    __syncthreads();
    // sort records into LDS
    #pragma unroll
    for (int k = 0; k < CHUNK / 256; k++) {
        int i = k * 256 + t;
        if (i < cnt) {
            int c = cols[base + i];
            int r = rows[base + i];
            int bkt = (unsigned)c / BRANGE;
            int lp = atomicAdd(&lcur[bkt], 1);
            staged[lp] = ((unsigned)(c - bkt * BRANGE) << 24) | (unsigned)r;
            bktarr[lp] = (unsigned short)bkt;
        }
    }
    __syncthreads();
    // flat coalesced copy-out: consecutive i in a run -> consecutive gpos
    #pragma unroll
    for (int k = 0; k < CHUNK / 256; k++) {
        int i = k * 256 + t;
        if (i < cnt) {
            int bkt = bktarr[i];
            int pos = gbase[bkt] + (i - excl[bkt]);
            if (pos < CAPB) eb[(size_t)bkt * CAPB + pos] = staged[i];
        }
    }
}

// ---- phase 2: per-bucket node sort. Records staged in LDS once, wave-0 shfl
//      scan (no 16-barrier Hillis-Steele), rank into LDS srcl, COALESCED
//      copy-out to srcs2. Emits nsd=(start,deg). ----
__global__ __launch_bounds__(512) void sortn_kernel(const int* __restrict__ cur,
                                                    const unsigned* __restrict__ eb,
                                                    int* __restrict__ srcs2,
                                                    int2* __restrict__ nsd) {
    __shared__ unsigned recs[CAPB];
    __shared__ unsigned srcl[CAPB];
    __shared__ int hist[256];
    __shared__ int lcur[256];
    int b = blockIdx.x, t = threadIdx.x;
    if (t < 256) hist[t] = 0;
    __syncthreads();
    int cnt = min(cur[b * 16], CAPB);
    const unsigned* seg = eb + (size_t)b * CAPB;
    for (int i = t; i < cnt; i += 512) {
        unsigned r = seg[i];
        recs[i] = r;
        atomicAdd(&hist[r >> 24], 1);
    }
    __syncthreads();
    if (t < 64) {
        // wave-0 scan of 256 hist entries: 4 per lane + shfl scan of lane sums
        int e = t * 4;
        int h0 = hist[e], h1 = hist[e + 1], h2 = hist[e + 2], h3 = hist[e + 3];
        int lsum = h0 + h1 + h2 + h3;
        int inc = lsum;
        #pragma unroll
        for (int off = 1; off < 64; off <<= 1) {
            int v = __shfl_up(inc, off);
            if (t >= off) inc += v;
        }
        int ex = inc - lsum;                       // exclusive base for entry e
        int e0 = ex, e1 = ex + h0, e2 = e1 + h1, e3 = e2 + h2;
        lcur[e] = e0; lcur[e + 1] = e1; lcur[e + 2] = e2; lcur[e + 3] = e3;
        int n = b * BRANGE + e;
        if (e     < BRANGE && n     < NN) nsd[n]     = make_int2(e0, h0);
        if (e + 1 < BRANGE && n + 1 < NN) nsd[n + 1] = make_int2(e1, h1);
        if (e + 2 < BRANGE && n + 2 < NN) nsd[n + 2] = make_int2(e2, h2);
        if (e + 3 < BRANGE && n + 3 < NN) nsd[n + 3] = make_int2(e3, h3);
    }
    __syncthreads();
    for (int i = t; i < cnt; i += 512) {
        unsigned r = recs[i];
        int p = atomicAdd(&lcur[r >> 24], 1);
        srcl[p] = r & 0xFFFFFFu;
    }
    __syncthreads();
    for (int i = t; i < cnt; i += 512)
        srcs2[(size_t)b * CAPB + i] = (int)srcl[i];
}

// ---- xs = bf16(x * rsqrt(deg+1)) : standalone, high-TLP dense stream ----
__global__ __launch_bounds__(256) void xscale_kernel(const float* __restrict__ x,
                                                     const int2* __restrict__ nsd,
                                                     unsigned* __restrict__ xs) {
    int i = blockIdx.x * 256 + threadIdx.x;           // NN*32 threads exactly
    int n = i >> 5;
    int d = (i & 31) * 2;
    float2 v = *(const float2*)(x + (size_t)n * 64 + d);
    float dv = rsqrtf((float)(nsd[n].y + 1));
    xs[i] = bf16x2_pack(v.x * dv, v.y * dv);
}

// ---- phase 3: gather-aggregate. 4 nodes/wave (16-lane groups, dwordx2 rows),
//      full-grid occupancy, 16 rows in flight per group ----
__global__ __launch_bounds__(256) void gather_kernel(const int* __restrict__ srcs2,
                                                     const int2* __restrict__ nsd,
                                                     const unsigned* __restrict__ xs,
                                                     unsigned* __restrict__ hbu) {
    int lane = threadIdx.x & 63;
    int wave = threadIdx.x >> 6;
    int g  = lane >> 4;            // group (node) within wave: 0..3
    int gl = lane & 15;            // lane within group: covers dims [gl*4, gl*4+4)
    int gb = g << 4;               // group's base lane

    int n = blockIdx.x * 16 + wave * 4 + g;           // grid = NN/16 = 6250 exact
    int2 sd = nsd[n];
    int deg = sd.y;
    int bkt = (unsigned)n / BRANGE;
    const int* seg = srcs2 + (size_t)bkt * CAPB + sd.x;
    const uint2* xsv = (const uint2*)xs;              // 8B per lane per row

    float4 acc = make_float4(0.f, 0.f, 0.f, 0.f);
    for (int base = 0; base < deg; base += 16) {
        // preload up to 16 edge indices for this group's node (one vector load)
        int idx = 0;
        if (base + gl < deg) idx = seg[base + gl];
        int s0 = __shfl(idx, gb);                     // always-valid line (base < deg)
        uint2 v[16];
        #pragma unroll
        for (int j = 0; j < 16; j++) {
            int s = __shfl(idx, gb + j);
            // clamp OOB lanes to a line the group fetches anyway: no serial
            // remainder, no hot pad line, all 16 loads issued back-to-back
            s = (base + j < deg) ? s : s0;
            v[j] = xsv[(size_t)s * 16 + gl];
        }
        #pragma unroll
        for (int j = 0; j < 16; j++) {
            if (base + j < deg) {
                float2 f0 = bf16x2_unpack(v[j].x);
                float2 f1 = bf16x2_unpack(v[j].y);
                acc.x += f0.x; acc.y += f0.y;
                acc.z += f1.x; acc.w += f1.y;
            }
        }
    }
    // self-loop + final D^-1/2 scale; each group stores its full node row (8B/lane)
    uint2 svu = xsv[(size_t)n * 16 + gl];
    float2 sv0 = bf16x2_unpack(svu.x);
    float2 sv1 = bf16x2_unpack(svu.y);
    float dn = rsqrtf((float)(deg + 1));
    uint2 o;
    o.x = bf16x2_pack((acc.x + sv0.x) * dn, (acc.y + sv0.y) * dn);
    o.y = bf16x2_pack((acc.z + sv1.x) * dn, (acc.w + sv1.y) * dn);
    ((uint2*)hbu)[(size_t)n * 16 + gl] = o;
}

// ---- pack Wcat[64 x 192] (3 experts side by side) into B-fragment order, bf16 ----
__global__ void wpack_kernel(const float* __restrict__ W, __hip_bfloat16* __restrict__ Bp) {
    int idx = blockIdx.x * 256 + threadIdx.x;         // 12288 total
    if (idx >= 12288) return;
    int j    = idx & 7;
    int lane = (idx >> 3) & 63;
    int rest = idx >> 9;                              // half*12 + t
    int t    = rest % 12;
    int kh   = rest / 12;
    int k    = kh * 32 + (lane >> 4) * 8 + j;
    int col  = t * 16 + (lane & 15);
    int i    = col >> 6;
    int d    = col & 63;
    Bp[idx] = __float2bfloat16(W[(i * 64 + k) * 64 + d]);
}

// ---- dense: [16-node tile] x [192 outs], K=64 bf16 MFMA; fused bias+relu+gate mix ----
__global__ __launch_bounds__(256) void mfma_kernel(const __hip_bfloat16* __restrict__ hb,
                                                   const short* __restrict__ Bp,
                                                   const float* __restrict__ b,
                                                   const float* __restrict__ gf,
                                                   const float* __restrict__ Wg,
                                                   float* __restrict__ out) {
    int wave = threadIdx.x >> 6;
    int lane = threadIdx.x & 63;
    int tile = blockIdx.x * 4 + wave;
    if (tile >= NT) return;
    int n0 = tile * 16;
    int m = lane & 15, quad = lane >> 4;

    const short* hrow = (const short*)hb + ((size_t)(n0 + m)) * 64 + quad * 8;
    bf16x8 a0 = *(const bf16x8*)(hrow);
    bf16x8 a1 = *(const bf16x8*)(hrow + 32);

    f32x4 acc[12];
    #pragma unroll
    for (int t = 0; t < 12; t++) acc[t] = (f32x4)(0.0f);

    #pragma unroll
    for (int kh = 0; kh < 2; kh++) {
        bf16x8 a = kh ? a1 : a0;
        #pragma unroll
        for (int t = 0; t < 12; t++) {
            bf16x8 bf = *(const bf16x8*)(Bp + ((size_t)((kh * 12 + t) * 64 + lane)) * 8);
            acc[t] = __builtin_amdgcn_mfma_f32_16x16x32_bf16(a, bf, acc[t], 0, 0, 0);
        }
    }

    float wg[12];
    #pragma unroll
    for (int k = 0; k < 12; k++) wg[k] = Wg[k];       // [GATE_C=4][EXPERTS=3] row-major

    #pragma unroll
    for (int reg = 0; reg < 4; reg++) {
        int n = n0 + quad * 4 + reg;
        float4 g = ((const float4*)gf)[n];
        float l0 = (g.x*wg[0] + g.y*wg[3] + g.z*wg[6] + g.w*wg[9])  * (1.0f/101.0f);
        float l1 = (g.x*wg[1] + g.y*wg[4] + g.z*wg[7] + g.w*wg[10]) * (1.0f/101.0f);
        float l2 = (g.x*wg[2] + g.y*wg[5] + g.z*wg[8] + g.w*wg[11]) * (1.0f/101.0f);
        float mx = fmaxf(l0, fmaxf(l1, l2));
        float e0 = __expf(l0 - mx), e1 = __expf(l1 - mx), e2 = __expf(l2 - mx);
        float inv = 1.0f / (e0 + e1 + e2);
        float g0 = e0 * inv, g1 = e1 * inv, g2 = e2 * inv;
        #pragma unroll
        for (int dpos = 0; dpos < 4; dpos++) {
            int d = dpos * 16 + m;
            float v0 = acc[0*4 + dpos][reg] + b[0*64 + d];
            float v1 = acc[1*4 + dpos][reg] + b[1*64 + d];
            float v2 = acc[2*4 + dpos][reg] + b[2*64 + d];
            float o = g0 * fmaxf(v0, 0.f) + g1 * fmaxf(v1, 0.f) + g2 * fmaxf(v2, 0.f);
            out[(size_t)n * 64 + d] = o;
        }
    }
}

extern "C" void kernel_launch(void* const* d_in, const int* in_sizes, int n_in,
                              void* d_out, int out_size, void* d_ws, size_t ws_size,
                              hipStream_t stream) {
    const float* x  = (const float*)d_in[0];
    const int*   ei = (const int*)d_in[1];
    const float* gf = (const float*)d_in[2];
    const float* W  = (const float*)d_in[3];
    const float* b  = (const float*)d_in[4];
    const float* Wg = (const float*)d_in[5];
    float* out = (float*)d_out;
    const int* rows = ei;        // edge_index[0] (sources)
    const int* cols = ei + NE;   // edge_index[1] (targets)

    char* ws = (char*)d_ws;
    size_t off = 0;
    auto alloc = [&](size_t bytes) {
        char* p = ws + off;
        off = (off + bytes + 255) & ~(size_t)255;
        return p;
    };
    int*            cur   = (int*)alloc(512 * 16 * 4);     // 1 counter / 64B line
    unsigned*       eb    = (unsigned*)alloc((size_t)NBUCK * CAPB * 4);
    int*            srcs2 = (int*)alloc((size_t)NBUCK * CAPB * 4);
    int2*           nsd   = (int2*)alloc((size_t)NN * 8);
    unsigned*       xs    = (unsigned*)alloc((size_t)NN * 32 * 4);
    unsigned*       hbu   = (unsigned*)alloc((size_t)NN * 32 * 4);
    __hip_bfloat16* Bp    = (__hip_bfloat16*)alloc(12288 * 2);

    hipMemsetAsync(cur, 0, 512 * 16 * 4, stream);

    bin_kernel<<<NCH, 256, 0, stream>>>(rows, cols, cur, eb);
    sortn_kernel<<<NBUCK, 512, 0, stream>>>(cur, eb, srcs2, nsd);
    xscale_kernel<<<NN * 32 / 256, 256, 0, stream>>>(x, nsd, xs);
    wpack_kernel<<<48, 256, 0, stream>>>(W, Bp);
    gather_kernel<<<NN / 16, 256, 0, stream>>>(srcs2, nsd, xs, hbu);
    mfma_kernel<<<(NT + 3) / 4, 256, 0, stream>>>((const __hip_bfloat16*)hbu,
                                                  (const short*)Bp, b, gf, Wg, out);
}